// Round 9
// baseline (995.661 us; speedup 1.0000x reference)
//
#include <hip/hip_runtime.h>
#include <hip/hip_bf16.h>

// 2-layer LSTM (H=20) + FC(20->1), B=4096, T=512, D_in=1.
//
// Round-9 structure: ROLE-SPLIT SOFTWARE PIPELINE.
// Evidence from rounds 1-8: the allocator never grants >~60-96 arch VGPRs
// and parks larger per-lane arrays in AGPRs; gfx950 VALU cannot source
// AGPRs (round-8 compile error), so every parked value costs an extra
// v_accvgpr_read per use (~2.5-3x instruction inflation, VALU-issue-bound
// at 86-96%). Fix: shrink per-lane live state to ~22 weights + one 20-float
// h vector, by splitting work across 12 waves (768 threads) per block:
//   waves 0-3  (role 0): layer-0 gate rw: Whh0 row + Wih0 scalar + bias.
//   waves 4-7  (role 1): layer-1 partial p = Wih1_row . h0  (20 weights).
//   waves 8-11 (role 2): layer-1 partial q = Whh1_row . h1 + bias,
//                        gate = p + q, finalize c1/h1.
// Pipeline stagger: at iteration i, role 0 computes step i (and finalizes
// h0(i-1)), role 1 computes p(i-2), role 2 consumes a1(i-4) -> h1(i-4) and
// emits a1(i-3). NITER = T+4 = 516, ONE barrier per iteration.
// All cross-wave buffers (act0/act1/p/h0-rows) parity double-buffered;
// h1 rows wave-private (intra-wave RAW needs no barrier). Exchange region
// zero-initialized so pre-pipeline iterations read exact zeros (state stays
// 0); role 2's finalize is guarded (i>=4) because sigm(bias) != 0.
// Lanes: [20g, 20g+19] = group g (batch b = 3*blk + g); lane j = unit j.

namespace {
constexpr int H_    = 20;
constexpr int T_    = 512;
constexpr int B_    = 4096;
constexpr int GPB   = 3;        // batch elements per block
constexpr int NITER = T_ + 4;   // pipeline depth 4

// LDS layout (float indices); all section bases 16B-aligned.
constexpr int XS  = 0;            // x     [GPB][T_+1]   (1539, +1 pad)
constexpr int A0  = 1540;         // act0  [2][4][64]    (512)
constexpr int A1  = A0 + 512;     // act1  [2][4][64]    (512)
constexpr int PS  = A1 + 512;     // p     [2][4][64]    (512)
constexpr int H0S = PS + 512;     // h0    [2][4][4][28] (896)
constexpr int H1S = H0S + 896;    // h1    [4][4][28]    (448)
constexpr int SME = H1S + 448;    // 4420 floats = 17.7 KB

__device__ __forceinline__ float sigm(float v) {
    return 1.0f / (1.0f + __expf(-v));
}
__device__ __forceinline__ float tanh_fast(float v) {
    return 1.0f - 2.0f / (1.0f + __expf(2.0f * v));
}
} // namespace

__global__ __launch_bounds__(768, 6) void lstm2_fc_kernel(
    const float* __restrict__ x,
    const float* __restrict__ Wih0, const float* __restrict__ Whh0,
    const float* __restrict__ bih0, const float* __restrict__ bhh0,
    const float* __restrict__ Wih1, const float* __restrict__ Whh1,
    const float* __restrict__ bih1, const float* __restrict__ bhh1,
    const float* __restrict__ fcW,  const float* __restrict__ fcb,
    float* __restrict__ out)
{
    const int tid  = threadIdx.x;
    const int wv   = __builtin_amdgcn_readfirstlane(tid >> 6); // 0..11 (SGPR)
    const int role = wv >> 2;           // 0,1,2
    const int rw   = wv & 3;            // gate index (torch order i,f,g,o)
    const int lane = tid & 63;
    const int g    = lane / H_;         // group 0..2 active, 3 = pad
    const int j    = lane - g * H_;     // hidden unit 0..19
    const int b    = blockIdx.x * GPB + g;
    const bool st  = (g < GPB) && (b < B_);
    const int  gx  = (g < GPB) ? g : (GPB - 1);

    __shared__ __align__(16) float smem[SME];

    // ---- stage x (coalesced) + zero the exchange region ----
    {
        const int base_b = blockIdx.x * GPB;
        for (int idx = tid; idx < GPB * T_; idx += 768) {
            const int gg = idx >> 9;          // /512
            const int tt = idx & (T_ - 1);    // %512
            int row = base_b + gg; if (row >= B_) row = B_ - 1;
            smem[XS + gg * (T_ + 1) + tt] = x[(size_t)row * T_ + tt];
        }
        for (int idx = tid; idx < SME - A0; idx += 768) smem[A0 + idx] = 0.0f;
    }

    // ---- per-role weights: at most 22 floats per lane ----
    const int r = rw * H_ + j;
    float wta[H_];
    float wx = 0.0f, bscal = 0.0f;
    if (role == 0) {
        wx = Wih0[r];                   // Wih0 is [80,1]
        bscal = bih0[r] + bhh0[r];
        #pragma unroll
        for (int k = 0; k < H_; ++k) wta[k] = Whh0[r * H_ + k];
    } else if (role == 1) {
        #pragma unroll
        for (int k = 0; k < H_; ++k) wta[k] = Wih1[r * H_ + k];
    } else {
        bscal = bih1[r] + bhh1[r];
        #pragma unroll
        for (int k = 0; k < H_; ++k) wta[k] = Whh1[r * H_ + k];
    }
    asm volatile("" : "+v"(wx), "+v"(bscal));
    #pragma unroll
    for (int k = 0; k < H_; ++k) asm volatile("" : "+v"(wta[k]));

    // ---- per-role state ----
    float hvec[H_];                     // h0 (roles 0,1) / h1 (role 2)
    #pragma unroll
    for (int k = 0; k < H_; ++k) hvec[k] = 0.0f;
    float cst = 0.0f;                   // c0 (role 0) / c1 (role 2)

    __syncthreads();                    // xs + zeros visible

    #pragma unroll 1
    for (int i = 0; i < NITER; ++i) {
        const int p0 = i & 1;
        const int p1 = p0 ^ 1;

        if (role == 0) {
            // finalize h0(i-1) from act0 quad (exact zeros at i=0)
            const int aq = A0 + p1 * 256 + lane;
            const float i0 = smem[aq      ];
            const float f0 = smem[aq +  64];
            const float z0 = smem[aq + 128];
            const float o0 = smem[aq + 192];
            cst = fmaf(f0, cst, i0 * z0);
            const float hn = o0 * tanh_fast(cst);
            const int hrow = H0S + ((p0 * 4 + rw) * 4 + g) * 28;
            smem[hrow + j] = hn;                       // own row (intra-wave)
            const float4* rp = reinterpret_cast<const float4*>(&smem[hrow]);
            #pragma unroll
            for (int c4 = 0; c4 < 5; ++c4) {
                const float4 v = rp[c4];
                hvec[c4*4+0] = v.x; hvec[c4*4+1] = v.y;
                hvec[c4*4+2] = v.z; hvec[c4*4+3] = v.w;
            }
            // gate0(i)
            const float xv = smem[XS + gx * (T_ + 1) + ((i < T_) ? i : (T_ - 1))];
            float s0 = fmaf(wx, xv, bscal), s1 = 0.f, s2 = 0.f, s3 = 0.f;
            #pragma unroll
            for (int k = 0; k < H_; k += 4) {
                s0 = fmaf(wta[k+0], hvec[k+0], s0);
                s1 = fmaf(wta[k+1], hvec[k+1], s1);
                s2 = fmaf(wta[k+2], hvec[k+2], s2);
                s3 = fmaf(wta[k+3], hvec[k+3], s3);
            }
            const float gate = (s0 + s1) + (s2 + s3);
            const float a = (rw == 2) ? tanh_fast(gate) : sigm(gate);
            smem[A0 + p0 * 256 + rw * 64 + lane] = a;
        } else if (role == 1) {
            // p(i-2) = Wih1_row . h0(i-2)   (h0 row written last iteration)
            const int hrow = H0S + ((p1 * 4 + rw) * 4 + g) * 28;
            const float4* rp = reinterpret_cast<const float4*>(&smem[hrow]);
            #pragma unroll
            for (int c4 = 0; c4 < 5; ++c4) {
                const float4 v = rp[c4];
                hvec[c4*4+0] = v.x; hvec[c4*4+1] = v.y;
                hvec[c4*4+2] = v.z; hvec[c4*4+3] = v.w;
            }
            float s0 = 0.f, s1 = 0.f, s2 = 0.f, s3 = 0.f;
            #pragma unroll
            for (int k = 0; k < H_; k += 4) {
                s0 = fmaf(wta[k+0], hvec[k+0], s0);
                s1 = fmaf(wta[k+1], hvec[k+1], s1);
                s2 = fmaf(wta[k+2], hvec[k+2], s2);
                s3 = fmaf(wta[k+3], hvec[k+3], s3);
            }
            smem[PS + p0 * 256 + rw * 64 + lane] = (s0 + s1) + (s2 + s3);
        } else {
            // finalize h1(i-4); guard: pre-pipeline a1 values are sigm(bias)!=0
            if (i >= 4) {
                const int aq = A1 + p1 * 256 + lane;
                const float i1 = smem[aq      ];
                const float f1 = smem[aq +  64];
                const float z1 = smem[aq + 128];
                const float o1 = smem[aq + 192];
                cst = fmaf(f1, cst, i1 * z1);
                const float hn = o1 * tanh_fast(cst);
                const int hrow = H1S + (rw * 4 + g) * 28;
                smem[hrow + j] = hn;                   // wave-private row
                const float4* rp = reinterpret_cast<const float4*>(&smem[hrow]);
                #pragma unroll
                for (int c4 = 0; c4 < 5; ++c4) {
                    const float4 v = rp[c4];
                    hvec[c4*4+0] = v.x; hvec[c4*4+1] = v.y;
                    hvec[c4*4+2] = v.z; hvec[c4*4+3] = v.w;
                }
            }
            // q(i-3) + p(i-3) -> a1(i-3)
            float s0 = bscal, s1 = 0.f, s2 = 0.f, s3 = 0.f;
            #pragma unroll
            for (int k = 0; k < H_; k += 4) {
                s0 = fmaf(wta[k+0], hvec[k+0], s0);
                s1 = fmaf(wta[k+1], hvec[k+1], s1);
                s2 = fmaf(wta[k+2], hvec[k+2], s2);
                s3 = fmaf(wta[k+3], hvec[k+3], s3);
            }
            const float pv = smem[PS + p1 * 256 + rw * 64 + lane];
            const float gate = ((s0 + s1) + (s2 + s3)) + pv;
            const float a = (rw == 2) ? tanh_fast(gate) : sigm(gate);
            smem[A1 + p0 * 256 + rw * 64 + lane] = a;
        }
        __syncthreads();
    }

    // ---- FC epilogue: role-2 wave 8 holds h1(T-1) in hvec ----
    if (role == 2 && rw == 0 && st && j == 0) {
        float acc = fcb[0];
        #pragma unroll
        for (int k = 0; k < H_; ++k) acc = fmaf(fcW[k], hvec[k], acc);
        out[b] = acc;
    }
}

extern "C" void kernel_launch(void* const* d_in, const int* in_sizes, int n_in,
                              void* d_out, int out_size, void* d_ws, size_t ws_size,
                              hipStream_t stream) {
    const float* x    = (const float*)d_in[0];
    const float* Wih0 = (const float*)d_in[1];
    const float* Whh0 = (const float*)d_in[2];
    const float* bih0 = (const float*)d_in[3];
    const float* bhh0 = (const float*)d_in[4];
    const float* Wih1 = (const float*)d_in[5];
    const float* Whh1 = (const float*)d_in[6];
    const float* bih1 = (const float*)d_in[7];
    const float* bhh1 = (const float*)d_in[8];
    const float* fcW  = (const float*)d_in[9];
    const float* fcb  = (const float*)d_in[10];
    float* out = (float*)d_out;

    const int grid = (B_ + GPB - 1) / GPB;   // 1366 blocks x 12 waves
    lstm2_fc_kernel<<<dim3(grid), dim3(768), 0, stream>>>(
        x, Wih0, Whh0, bih0, bhh0, Wih1, Whh1, bih1, bhh1, fcW, fcb, out);
}

// Round 11
// 884.354 us; speedup vs baseline: 1.1259x; 1.1259x over previous
//
#include <hip/hip_runtime.h>
#include <hip/hip_bf16.h>

// 2-layer LSTM (H=20) + FC(20->1), B=4096, T=512, D_in=1.
//
// Round-10/11: R5 structure (best, 820us) + TWO PLANES PER LANE.
// Evidence: R9 raised occupancy 32->58% with NO gain; VALUBusy pinned ~85%
// (gfx94x-formula double-counts wave64 -> true ~43%): we are latency/
// serialization-bound with issue headroom. Fix latency via ILP: each lane
// carries 2 independent sequences (planes). Weights are SHARED across
// planes (one weight-register read feeds 2 FMAs -> amortizes the AGPR
// parking tax R7 quantified), all latency windows (exp/rcp chains, LDS
// round trips, barrier skew) fill with the other plane's work.
// (Round-10 submission never executed: GPUAcquisitionTimeout. Resubmitted
// unchanged.)
//
// Mapping: block = 256 thr = 4 waves; wave w owns gate w (i,f,g,o order);
// lanes [20g,20g+19] = group g; lane j = hidden unit j; plane p in {0,1}:
// batch b = blk*6 + p*3 + g. 6 sequences/block, grid=683.
// Per step: 2 barriers (act exchange per layer, both planes in one go);
// c,h finalized redundantly in all 4 waves (bitwise-identical); h rows
// wave-private (intra-wave RAW, no barrier).

namespace {
constexpr int H_  = 20;
constexpr int T_  = 512;
constexpr int B_  = 4096;
constexpr int PL  = 2;              // planes (sequences per lane)
constexpr int GRP = 3;              // groups per wave
constexpr int GPB = PL * GRP;       // 6 sequences per block

__device__ __forceinline__ float sigm(float v) {
    return 1.0f / (1.0f + __expf(-v));
}
__device__ __forceinline__ float tanh_fast(float v) {
    return 1.0f - 2.0f / (1.0f + __expf(2.0f * v));
}
} // namespace

__global__ __launch_bounds__(256, 3) void lstm2_fc_kernel(
    const float* __restrict__ x,
    const float* __restrict__ Wih0, const float* __restrict__ Whh0,
    const float* __restrict__ bih0, const float* __restrict__ bhh0,
    const float* __restrict__ Wih1, const float* __restrict__ Whh1,
    const float* __restrict__ bih1, const float* __restrict__ bhh1,
    const float* __restrict__ fcW,  const float* __restrict__ fcb,
    float* __restrict__ out)
{
    const int tid  = threadIdx.x;
    const int w_s  = __builtin_amdgcn_readfirstlane(tid >> 6); // gate 0..3
    const int lane = tid & 63;
    const int g    = lane / H_;           // group 0..2 active, 3 = pad
    const int j    = lane - g * H_;       // hidden unit 0..19
    const int gx   = (g < GRP) ? g : (GRP - 1);

    __shared__ float xs[GPB][T_ + 1];                   // +1: pad slot t=512
    __shared__ float act0[PL][4][64];                   // [plane][gate][lane]
    __shared__ float act1[PL][4][64];
    __shared__ __align__(16) float h0s[4][PL][4][28];   // [wave][plane][grp][pad]
    __shared__ __align__(16) float h1s[4][PL][4][28];

    // ---- stage x rows for this block's 6 sequences (coalesced) ----
    {
        const int base_b = blockIdx.x * GPB;
        for (int idx = tid; idx < GPB * T_; idx += 256) {
            const int ss = idx >> 9;            // /512 -> seq slot 0..5
            const int tt = idx & (T_ - 1);      // %512
            int row = base_b + ss; if (row >= B_) row = B_ - 1;
            xs[ss][tt] = x[(size_t)row * T_ + tt];
        }
    }

    // ---- lane-private weights (shared by both planes): row r = w_s*20+j ----
    const int r = w_s * H_ + j;
    float w0x   = Wih0[r];                    // Wih0 is [80,1]
    float bias0 = bih0[r] + bhh0[r];
    float bias1 = bih1[r] + bhh1[r];
    float w0h[H_], w1i[H_], w1h[H_];
    #pragma unroll
    for (int k = 0; k < H_; ++k) {
        w0h[k] = Whh0[r * H_ + k];
        w1i[k] = Wih1[r * H_ + k];
        w1h[k] = Whh1[r * H_ + k];
    }
    asm volatile("" : "+v"(w0x), "+v"(bias0), "+v"(bias1));
    #pragma unroll
    for (int k = 0; k < H_; ++k) {
        asm volatile("" : "+v"(w0h[k]), "+v"(w1i[k]), "+v"(w1h[k]));
    }

    // ---- per-plane state (replicated across waves, bitwise-consistent) ----
    float h0r[PL][H_], h1r[PL][H_];
    float c0[PL], c1[PL];
    #pragma unroll
    for (int p = 0; p < PL; ++p) {
        c0[p] = 0.0f; c1[p] = 0.0f;
        #pragma unroll
        for (int k = 0; k < H_; ++k) { h0r[p][k] = 0.0f; h1r[p][k] = 0.0f; }
    }

    const float* xrow0 = &xs[0 * GRP + gx][0];
    const float* xrow1 = &xs[1 * GRP + gx][0];

    __syncthreads();                          // xs ready
    float xv[PL] = { xrow0[0], xrow1[0] };

    #pragma unroll 1
    for (int t = 0; t < T_; ++t) {
        // ========= layer 0: own gate row, both planes (8 FMA chains) =========
        float s[PL][4];
        #pragma unroll
        for (int p = 0; p < PL; ++p) {
            s[p][0] = fmaf(w0x, xv[p], bias0);
            s[p][1] = 0.0f; s[p][2] = 0.0f; s[p][3] = 0.0f;
        }
        #pragma unroll
        for (int k = 0; k < H_; k += 4) {
            #pragma unroll
            for (int q = 0; q < 4; ++q) {
                const float wk = w0h[k + q];          // 1 read, 2 FMAs
                s[0][q] = fmaf(wk, h0r[0][k + q], s[0][q]);
                s[1][q] = fmaf(wk, h0r[1][k + q], s[1][q]);
            }
        }
        #pragma unroll
        for (int p = 0; p < PL; ++p) {
            const float gate = (s[p][0] + s[p][1]) + (s[p][2] + s[p][3]);
            const float a = (w_s == 2) ? tanh_fast(gate) : sigm(gate);
            act0[p][w_s][lane] = a;
        }
        const float xn0 = xrow0[t + 1];       // pad slot at t=511; unused
        const float xn1 = xrow1[t + 1];
        __syncthreads();                                   // BAR 1

        #pragma unroll
        for (int p = 0; p < PL; ++p) {
            const float i0 = act0[p][0][lane];
            const float f0 = act0[p][1][lane];
            const float z0 = act0[p][2][lane];
            const float o0 = act0[p][3][lane];
            c0[p] = fmaf(f0, c0[p], i0 * z0);
            const float hn = o0 * tanh_fast(c0[p]);
            h0s[w_s][p][g][j] = hn;                        // wave-private row
            const float4* rp = reinterpret_cast<const float4*>(&h0s[w_s][p][gx][0]);
            #pragma unroll
            for (int c4 = 0; c4 < 5; ++c4) {
                const float4 v = rp[c4];
                h0r[p][c4*4+0] = v.x; h0r[p][c4*4+1] = v.y;
                h0r[p][c4*4+2] = v.z; h0r[p][c4*4+3] = v.w;
            }
        }

        // ========= layer 1: own gate row, both planes (8 chains) =========
        float u[PL][4];
        #pragma unroll
        for (int p = 0; p < PL; ++p) {
            u[p][0] = bias1; u[p][1] = 0.0f; u[p][2] = 0.0f; u[p][3] = 0.0f;
        }
        #pragma unroll
        for (int k = 0; k < H_; k += 2) {
            const float wa0 = w1i[k + 0], wa1 = w1i[k + 1];
            const float wb0 = w1h[k + 0], wb1 = w1h[k + 1];
            #pragma unroll
            for (int p = 0; p < PL; ++p) {
                u[p][0] = fmaf(wa0, h0r[p][k + 0], u[p][0]);
                u[p][1] = fmaf(wa1, h0r[p][k + 1], u[p][1]);
                u[p][2] = fmaf(wb0, h1r[p][k + 0], u[p][2]);
                u[p][3] = fmaf(wb1, h1r[p][k + 1], u[p][3]);
            }
        }
        #pragma unroll
        for (int p = 0; p < PL; ++p) {
            const float gate = (u[p][0] + u[p][1]) + (u[p][2] + u[p][3]);
            const float a = (w_s == 2) ? tanh_fast(gate) : sigm(gate);
            act1[p][w_s][lane] = a;
        }
        __syncthreads();                                   // BAR 2

        #pragma unroll
        for (int p = 0; p < PL; ++p) {
            const float i1 = act1[p][0][lane];
            const float f1 = act1[p][1][lane];
            const float z1 = act1[p][2][lane];
            const float o1 = act1[p][3][lane];
            c1[p] = fmaf(f1, c1[p], i1 * z1);
            const float hn = o1 * tanh_fast(c1[p]);
            h1s[w_s][p][g][j] = hn;                        // wave-private row
            const float4* rp = reinterpret_cast<const float4*>(&h1s[w_s][p][gx][0]);
            #pragma unroll
            for (int c4 = 0; c4 < 5; ++c4) {
                const float4 v = rp[c4];
                h1r[p][c4*4+0] = v.x; h1r[p][c4*4+1] = v.y;
                h1r[p][c4*4+2] = v.z; h1r[p][c4*4+3] = v.w;
            }
        }

        xv[0] = xn0; xv[1] = xn1;
    }

    // ================= FC epilogue =================
    if (w_s == 0 && g < GRP && j == 0) {
        #pragma unroll
        for (int p = 0; p < PL; ++p) {
            const int b = blockIdx.x * GPB + p * GRP + g;
            if (b < B_) {
                float acc = fcb[0];
                #pragma unroll
                for (int k = 0; k < H_; ++k) acc = fmaf(fcW[k], h1r[p][k], acc);
                out[b] = acc;
            }
        }
    }
}

extern "C" void kernel_launch(void* const* d_in, const int* in_sizes, int n_in,
                              void* d_out, int out_size, void* d_ws, size_t ws_size,
                              hipStream_t stream) {
    const float* x    = (const float*)d_in[0];
    const float* Wih0 = (const float*)d_in[1];
    const float* Whh0 = (const float*)d_in[2];
    const float* bih0 = (const float*)d_in[3];
    const float* bhh0 = (const float*)d_in[4];
    const float* Wih1 = (const float*)d_in[5];
    const float* Whh1 = (const float*)d_in[6];
    const float* bih1 = (const float*)d_in[7];
    const float* bhh1 = (const float*)d_in[8];
    const float* fcW  = (const float*)d_in[9];
    const float* fcb  = (const float*)d_in[10];
    float* out = (float*)d_out;

    const int grid = (B_ + GPB - 1) / GPB;   // 683 blocks x 4 waves
    lstm2_fc_kernel<<<dim3(grid), dim3(256), 0, stream>>>(
        x, Wih0, Whh0, bih0, bhh0, Wih1, Whh1, bih1, bhh1, fcW, fcb, out);
}

// Round 12
// 718.303 us; speedup vs baseline: 1.3861x; 1.2312x over previous
//
#include <hip/hip_runtime.h>
#include <hip/hip_bf16.h>

// 2-layer LSTM (H=20) + FC(20->1), B=4096, T=512, D_in=1.
//
// Round-12: R5 structure + ONE barrier/step + fast rcp.
// Evidence: R4/R5/R9/R11 all pinned at 820-1000us across occupancy 24-58%
// and different per-wave instruction mixes -> sync + hidden instruction
// taxes dominate. Two fixes:
//  1. Layer pipeline (1-deep): iter t computes gate0(t) AND gate1(t-1)
//     back-to-back (both read h0(t-1) from regs), ONE exchange + ONE
//     barrier, then finalizes h0(t) and h1(t-1) together. Barriers
//     1024 -> 513. Dots merge into 61 MACs of 8-chain ILP; the two
//     activation transcendental chains overlap.
//  2. 1.0f/x without fast-math = full v_div_scale/div_fmas sequence
//     (~10 instr, x3 per step, every round so far). Replace with raw
//     v_rcp_f32 (__builtin_amdgcn_rcpf, ~1 ulp; threshold is 6e-4 and
//     we pass at absmax 0.0).
// t=0 boundary branch-free: c1 *= keep (keep=0 only at t=0); tanh(0)=0
// exactly so h1 stays exactly 0 -> state entering t=1 is exact.
//
// Mapping: block = 256 thr = 4 waves, GPB=3 sequences; wave w owns gate w
// (i,f,g,o); lanes [20g,20g+19] = group g; lane j = unit j. act exchange
// parity double-buffered (write pre-barrier, read post-barrier); h rows
// wave-private (intra-wave RAW, no barrier).

namespace {
constexpr int H_  = 20;
constexpr int T_  = 512;
constexpr int B_  = 4096;
constexpr int GPB = 3;    // sequences per block

__device__ __forceinline__ float rcp_fast(float v) {
    return __builtin_amdgcn_rcpf(v);
}
__device__ __forceinline__ float sigm(float v) {
    return rcp_fast(1.0f + __expf(-v));
}
__device__ __forceinline__ float tanh_fast(float v) {
    // 1 - 2/(1+e^{2v}); tanh_fast(0) == 0 exactly (rcp(2)=0.5 exact)
    return fmaf(-2.0f, rcp_fast(1.0f + __expf(2.0f * v)), 1.0f);
}
} // namespace

__global__ __launch_bounds__(256, 3) void lstm2_fc_kernel(
    const float* __restrict__ x,
    const float* __restrict__ Wih0, const float* __restrict__ Whh0,
    const float* __restrict__ bih0, const float* __restrict__ bhh0,
    const float* __restrict__ Wih1, const float* __restrict__ Whh1,
    const float* __restrict__ bih1, const float* __restrict__ bhh1,
    const float* __restrict__ fcW,  const float* __restrict__ fcb,
    float* __restrict__ out)
{
    const int tid  = threadIdx.x;
    const int w_s  = __builtin_amdgcn_readfirstlane(tid >> 6); // gate 0..3
    const int lane = tid & 63;
    const int g    = lane / H_;           // group 0..2 active, 3 = pad
    const int j    = lane - g * H_;       // hidden unit 0..19
    const int b    = blockIdx.x * GPB + g;
    const bool st  = (g < GPB) && (b < B_);
    const int  gx  = (g < GPB) ? g : (GPB - 1);

    __shared__ float xs[GPB][T_ + 2];                // slots 512,513 zeroed
    __shared__ float act0[2][4][64];                 // [parity][gate][lane]
    __shared__ float act1[2][4][64];
    __shared__ __align__(16) float h0s[4][4][28];    // [wave][group][unit pad]
    __shared__ __align__(16) float h1s[4][4][28];

    // ---- stage x rows (coalesced); zero the 2 pad slots ----
    {
        const int base_b = blockIdx.x * GPB;
        for (int idx = tid; idx < GPB * T_; idx += 256) {
            const int gg = idx >> 9;            // /512
            const int tt = idx & (T_ - 1);      // %512
            int row = base_b + gg; if (row >= B_) row = B_ - 1;
            xs[gg][tt] = x[(size_t)row * T_ + tt];
        }
        if (tid < GPB * 2) xs[tid >> 1][T_ + (tid & 1)] = 0.0f;
    }

    // ---- lane-private weights: gate row r = w_s*20 + j ----
    const int r = w_s * H_ + j;
    float w0x   = Wih0[r];                           // Wih0 is [80,1]
    float bias0 = bih0[r] + bhh0[r];
    float bias1 = bih1[r] + bhh1[r];
    float w0h[H_], w1i[H_], w1h[H_];
    #pragma unroll
    for (int k = 0; k < H_; ++k) {
        w0h[k] = Whh0[r * H_ + k];
        w1i[k] = Wih1[r * H_ + k];
        w1h[k] = Whh1[r * H_ + k];
    }
    asm volatile("" : "+v"(w0x), "+v"(bias0), "+v"(bias1));
    #pragma unroll
    for (int k = 0; k < H_; ++k) {
        asm volatile("" : "+v"(w0h[k]), "+v"(w1i[k]), "+v"(w1h[k]));
    }

    // ---- state (replicated across waves, bitwise-consistent) ----
    // entering iter t: h0r = h0(t-1), h1r = h1(t-2), c0 = c0(t-1), c1 = c1(t-2)
    float h0r[H_], h1r[H_];
    #pragma unroll
    for (int k = 0; k < H_; ++k) { h0r[k] = 0.0f; h1r[k] = 0.0f; }
    float c0 = 0.0f, c1 = 0.0f;

    const float4* h0row = reinterpret_cast<const float4*>(&h0s[w_s][gx][0]);
    const float4* h1row = reinterpret_cast<const float4*>(&h1s[w_s][gx][0]);
    const float*  xrow  = &xs[gx][0];

    __syncthreads();                                 // xs ready
    float xv = xrow[0];

    #pragma unroll 1
    for (int t = 0; t <= T_; ++t) {
        const int par = t & 1;
        // ===== phase A: gate0(t) and gate1(t-1), merged 61-MAC block =====
        float s0 = fmaf(w0x, xv, bias0);
        float s1 = 0.0f, s2 = 0.0f, s3 = 0.0f;
        float u0 = bias1, u1 = 0.0f, u2 = 0.0f, u3 = 0.0f;
        #pragma unroll
        for (int k = 0; k < H_; k += 4) {
            s0 = fmaf(w0h[k + 0], h0r[k + 0], s0);
            s1 = fmaf(w0h[k + 1], h0r[k + 1], s1);
            s2 = fmaf(w0h[k + 2], h0r[k + 2], s2);
            s3 = fmaf(w0h[k + 3], h0r[k + 3], s3);
            u0 = fmaf(w1i[k + 0], h0r[k + 0], u0);
            u1 = fmaf(w1i[k + 1], h0r[k + 1], u1);
            u2 = fmaf(w1h[k + 0], h1r[k + 0], u2);
            u3 = fmaf(w1h[k + 1], h1r[k + 1], u3);
            u0 = fmaf(w1i[k + 2], h0r[k + 2], u0);
            u1 = fmaf(w1i[k + 3], h0r[k + 3], u1);
            u2 = fmaf(w1h[k + 2], h1r[k + 2], u2);
            u3 = fmaf(w1h[k + 3], h1r[k + 3], u3);
        }
        const float gate0 = (s0 + s1) + (s2 + s3);
        const float gate1 = (u0 + u1) + (u2 + u3);
        float a0, a1;
        if (w_s == 2) { a0 = tanh_fast(gate0); a1 = tanh_fast(gate1); }
        else          { a0 = sigm(gate0);      a1 = sigm(gate1); }
        act0[par][w_s][lane] = a0;
        act1[par][w_s][lane] = a1;
        const float xnext = xrow[t + 1];             // pad slot beyond 511
        __syncthreads();                             // THE barrier

        // ===== phase B: finalize h0(t) and h1(t-1) together =====
        const float i0 = act0[par][0][lane];
        const float f0 = act0[par][1][lane];
        const float z0 = act0[par][2][lane];
        const float o0 = act0[par][3][lane];
        const float i1 = act1[par][0][lane];
        const float f1 = act1[par][1][lane];
        const float z1 = act1[par][2][lane];
        const float o1 = act1[par][3][lane];

        c0 = fmaf(f0, c0, i0 * z0);
        const float h0n = o0 * tanh_fast(c0);
        const float keep = (t == 0) ? 0.0f : 1.0f;   // kill bogus gate1(-1)
        c1 = fmaf(f1, c1, i1 * z1) * keep;
        const float h1n = o1 * tanh_fast(c1);        // exact 0 at t=0

        h0s[w_s][g][j] = h0n;                        // wave-private rows
        h1s[w_s][g][j] = h1n;
        #pragma unroll
        for (int c4 = 0; c4 < 5; ++c4) {
            const float4 v0 = h0row[c4];
            h0r[c4*4+0] = v0.x; h0r[c4*4+1] = v0.y;
            h0r[c4*4+2] = v0.z; h0r[c4*4+3] = v0.w;
            const float4 v1 = h1row[c4];
            h1r[c4*4+0] = v1.x; h1r[c4*4+1] = v1.y;
            h1r[c4*4+2] = v1.z; h1r[c4*4+3] = v1.w;
        }

        xv = xnext;
    }

    // ===== FC epilogue: h1r = h1(T-1) in every wave =====
    if (w_s == 0 && st && j == 0) {
        float acc = fcb[0];
        #pragma unroll
        for (int k = 0; k < H_; ++k) acc = fmaf(fcW[k], h1r[k], acc);
        out[b] = acc;
    }
}

extern "C" void kernel_launch(void* const* d_in, const int* in_sizes, int n_in,
                              void* d_out, int out_size, void* d_ws, size_t ws_size,
                              hipStream_t stream) {
    const float* x    = (const float*)d_in[0];
    const float* Wih0 = (const float*)d_in[1];
    const float* Whh0 = (const float*)d_in[2];
    const float* bih0 = (const float*)d_in[3];
    const float* bhh0 = (const float*)d_in[4];
    const float* Wih1 = (const float*)d_in[5];
    const float* Whh1 = (const float*)d_in[6];
    const float* bih1 = (const float*)d_in[7];
    const float* bhh1 = (const float*)d_in[8];
    const float* fcW  = (const float*)d_in[9];
    const float* fcb  = (const float*)d_in[10];
    float* out = (float*)d_out;

    const int grid = (B_ + GPB - 1) / GPB;   // 1366 blocks x 4 waves
    lstm2_fc_kernel<<<dim3(grid), dim3(256), 0, stream>>>(
        x, Wih0, Whh0, bih0, bhh0, Wih1, Whh1, bih1, bhh1, fcW, fcb, out);
}

// Round 13
// 687.692 us; speedup vs baseline: 1.4478x; 1.0445x over previous
//
#include <hip/hip_runtime.h>
#include <hip/hip_bf16.h>

// 2-layer LSTM (H=20) + FC(20->1), B=4096, T=512, D_in=1.
//
// Round-13 = R12 (718us) + packed-FP32 math.
// R12 counters: VGPR=60 (weights AGPR-parked; ~61 hidden accvgpr_reads per
// step are structural since gfx950 VALU can't source AGPRs - R8), VALUBusy
// 76%, occ 33%. Per-step issue budget ~190; the FMA half is compressible:
//  1. v_pk_fma_f32 (VOP3P, CDNA2+): 2 MACs per issue slot. h state held
//     natively as f32x2[10] per layer (b128 readback fills adjacent regs),
//     weights as f32x2 pairs. 61 FMA -> 30 pk + 1 scalar.
//  2. Act exchange packed {layer0,layer1} as f32x2: 1 ds_write_b64 +
//     4 ds_read_b64 (was 2+8 b32); shrinks the post-barrier latency window.
// Structure unchanged from R12: 1-deep layer pipeline (gate0(t)+gate1(t-1)
// per iter), ONE barrier/iter, fast rcp activations, redundant finalize in
// all 4 waves, wave-private h rows (intra-wave RAW, no barrier).
//
// Mapping: block = 256 thr = 4 waves, GPB=3 sequences; wave w owns gate w
// (i,f,g,o); lanes [20g,20g+19] = group g; lane j = unit j.

namespace {
constexpr int H_  = 20;
constexpr int T_  = 512;
constexpr int B_  = 4096;
constexpr int GPB = 3;    // sequences per block

typedef float __attribute__((ext_vector_type(2))) f32x2;

__device__ __forceinline__ float rcp_fast(float v) {
    return __builtin_amdgcn_rcpf(v);
}
__device__ __forceinline__ float sigm(float v) {
    return rcp_fast(1.0f + __expf(-v));
}
__device__ __forceinline__ float tanh_fast(float v) {
    // 1 - 2/(1+e^{2v}); tanh_fast(0) == 0 exactly
    return fmaf(-2.0f, rcp_fast(1.0f + __expf(2.0f * v)), 1.0f);
}
// Packed MAC: acc.{x,y} += a.{x,y} * b.{x,y} in ONE issue slot.
__device__ __forceinline__ void pk_mac(f32x2& acc, f32x2 a, f32x2 b) {
#if __has_builtin(__builtin_amdgcn_pk_fma_f32)
    acc = __builtin_amdgcn_pk_fma_f32(a, b, acc);
#else
    asm("v_pk_fma_f32 %0, %1, %2, %0" : "+v"(acc) : "v"(a), "v"(b));
#endif
}
} // namespace

__global__ __launch_bounds__(256, 3) void lstm2_fc_kernel(
    const float* __restrict__ x,
    const float* __restrict__ Wih0, const float* __restrict__ Whh0,
    const float* __restrict__ bih0, const float* __restrict__ bhh0,
    const float* __restrict__ Wih1, const float* __restrict__ Whh1,
    const float* __restrict__ bih1, const float* __restrict__ bhh1,
    const float* __restrict__ fcW,  const float* __restrict__ fcb,
    float* __restrict__ out)
{
    const int tid  = threadIdx.x;
    const int w_s  = __builtin_amdgcn_readfirstlane(tid >> 6); // gate 0..3
    const int lane = tid & 63;
    const int g    = lane / H_;           // group 0..2 active, 3 = pad
    const int j    = lane - g * H_;       // hidden unit 0..19
    const int b    = blockIdx.x * GPB + g;
    const bool st  = (g < GPB) && (b < B_);
    const int  gx  = (g < GPB) ? g : (GPB - 1);

    __shared__ float xs[GPB][T_ + 2];                // slots 512,513 zeroed
    __shared__ __align__(8)  f32x2 actP[2][4][64];   // [parity][gate][lane]={L0,L1}
    __shared__ __align__(16) float h0s[4][4][28];    // [wave][group][unit pad]
    __shared__ __align__(16) float h1s[4][4][28];

    // ---- stage x rows (coalesced); zero the 2 pad slots ----
    {
        const int base_b = blockIdx.x * GPB;
        for (int idx = tid; idx < GPB * T_; idx += 256) {
            const int gg = idx >> 9;            // /512
            const int tt = idx & (T_ - 1);      // %512
            int row = base_b + gg; if (row >= B_) row = B_ - 1;
            xs[gg][tt] = x[(size_t)row * T_ + tt];
        }
        if (tid < GPB * 2) xs[tid >> 1][T_ + (tid & 1)] = 0.0f;
    }

    // ---- lane-private weights as f32x2 pairs: gate row r = w_s*20 + j ----
    const int r = w_s * H_ + j;
    float w0x   = Wih0[r];                           // Wih0 is [80,1]
    float bias0 = bih0[r] + bhh0[r];
    float bias1 = bih1[r] + bhh1[r];
    f32x2 w0hP[10], w1iP[10], w1hP[10];
    #pragma unroll
    for (int m = 0; m < 10; ++m) {
        f32x2 a = { Whh0[r * H_ + 2*m], Whh0[r * H_ + 2*m + 1] };
        f32x2 c = { Wih1[r * H_ + 2*m], Wih1[r * H_ + 2*m + 1] };
        f32x2 d = { Whh1[r * H_ + 2*m], Whh1[r * H_ + 2*m + 1] };
        w0hP[m] = a; w1iP[m] = c; w1hP[m] = d;
    }
    asm volatile("" : "+v"(w0x), "+v"(bias0), "+v"(bias1));
    #pragma unroll
    for (int m = 0; m < 10; ++m) {
        asm volatile("" : "+v"(w0hP[m]), "+v"(w1iP[m]), "+v"(w1hP[m]));
    }

    // ---- state as pairs (replicated across waves, bitwise-consistent) ----
    // entering iter t: h0p = h0(t-1), h1p = h1(t-2), c0 = c0(t-1), c1 = c1(t-2)
    f32x2 h0p[10], h1p[10];
    #pragma unroll
    for (int m = 0; m < 10; ++m) {
        f32x2 z = {0.0f, 0.0f};
        h0p[m] = z; h1p[m] = z;
    }
    float c0 = 0.0f, c1 = 0.0f;

    const float4* h0row = reinterpret_cast<const float4*>(&h0s[w_s][gx][0]);
    const float4* h1row = reinterpret_cast<const float4*>(&h1s[w_s][gx][0]);
    const float*  xrow  = &xs[gx][0];

    __syncthreads();                                 // xs ready
    float xv = xrow[0];

    #pragma unroll 1
    for (int t = 0; t <= T_; ++t) {
        const int par = t & 1;
        // ===== phase A: gate0(t) and gate1(t-1), packed 31-slot dot =====
        f32x2 sA = {0.f, 0.f}, sB = {0.f, 0.f};
        f32x2 uA = {0.f, 0.f}, uB = {0.f, 0.f};
        f32x2 vA = {0.f, 0.f}, vB = {0.f, 0.f};
        #pragma unroll
        for (int m = 0; m < 10; m += 2) {
            pk_mac(sA, w0hP[m    ], h0p[m    ]);
            pk_mac(sB, w0hP[m + 1], h0p[m + 1]);
            pk_mac(uA, w1iP[m    ], h0p[m    ]);
            pk_mac(uB, w1iP[m + 1], h0p[m + 1]);
            pk_mac(vA, w1hP[m    ], h1p[m    ]);
            pk_mac(vB, w1hP[m + 1], h1p[m + 1]);
        }
        const float gate0 = fmaf(w0x, xv, bias0) + ((sA.x + sA.y) + (sB.x + sB.y));
        const float gate1 = (bias1 + ((uA.x + uA.y) + (uB.x + uB.y)))
                          + ((vA.x + vA.y) + (vB.x + vB.y));
        float a0, a1;
        if (w_s == 2) { a0 = tanh_fast(gate0); a1 = tanh_fast(gate1); }
        else          { a0 = sigm(gate0);      a1 = sigm(gate1); }
        f32x2 aw = { a0, a1 };
        actP[par][w_s][lane] = aw;                   // one ds_write_b64
        const float xnext = xrow[t + 1];             // pad slot beyond 511
        __syncthreads();                             // THE barrier

        // ===== phase B: finalize h0(t) and h1(t-1) together =====
        const f32x2 i01 = actP[par][0][lane];        // 4x ds_read_b64
        const f32x2 f01 = actP[par][1][lane];
        const f32x2 z01 = actP[par][2][lane];
        const f32x2 o01 = actP[par][3][lane];

        c0 = fmaf(f01.x, c0, i01.x * z01.x);
        const float h0n = o01.x * tanh_fast(c0);
        const float keep = (t == 0) ? 0.0f : 1.0f;   // kill bogus gate1(-1)
        c1 = fmaf(f01.y, c1, i01.y * z01.y) * keep;
        const float h1n = o01.y * tanh_fast(c1);     // exact 0 at t=0

        h0s[w_s][g][j] = h0n;                        // wave-private rows
        h1s[w_s][g][j] = h1n;
        #pragma unroll
        for (int c4 = 0; c4 < 5; ++c4) {
            const float4 v0 = h0row[c4];
            f32x2 p0a = { v0.x, v0.y }, p0b = { v0.z, v0.w };
            h0p[2*c4] = p0a; h0p[2*c4+1] = p0b;
            const float4 v1 = h1row[c4];
            f32x2 p1a = { v1.x, v1.y }, p1b = { v1.z, v1.w };
            h1p[2*c4] = p1a; h1p[2*c4+1] = p1b;
        }

        xv = xnext;
    }

    // ===== FC epilogue: h1p = h1(T-1) in every wave =====
    if (w_s == 0 && st && j == 0) {
        float acc = fcb[0];
        #pragma unroll
        for (int m = 0; m < 10; ++m) {
            acc = fmaf(fcW[2*m    ], h1p[m].x, acc);
            acc = fmaf(fcW[2*m + 1], h1p[m].y, acc);
        }
        out[b] = acc;
    }
}

extern "C" void kernel_launch(void* const* d_in, const int* in_sizes, int n_in,
                              void* d_out, int out_size, void* d_ws, size_t ws_size,
                              hipStream_t stream) {
    const float* x    = (const float*)d_in[0];
    const float* Wih0 = (const float*)d_in[1];
    const float* Whh0 = (const float*)d_in[2];
    const float* bih0 = (const float*)d_in[3];
    const float* bhh0 = (const float*)d_in[4];
    const float* Wih1 = (const float*)d_in[5];
    const float* Whh1 = (const float*)d_in[6];
    const float* bih1 = (const float*)d_in[7];
    const float* bhh1 = (const float*)d_in[8];
    const float* fcW  = (const float*)d_in[9];
    const float* fcb  = (const float*)d_in[10];
    float* out = (float*)d_out;

    const int grid = (B_ + GPB - 1) / GPB;   // 1366 blocks x 4 waves
    lstm2_fc_kernel<<<dim3(grid), dim3(256), 0, stream>>>(
        x, Wih0, Whh0, bih0, bhh0, Wih1, Whh1, bih1, bhh1, fcW, fcb, out);
}